// Round 1
// baseline (601.298 us; speedup 1.0000x reference)
//
#include <hip/hip_runtime.h>

#define NSEG 4096
#define SC (NSEG * 2)   // segments * channels

// ---------------------------------------------------------------------------
// Pass 1: per-segment sum of exp(x) for both (xab,src) and (xba,tar).
// LDS pre-reduction (64 KB: two 32 KB tables), then global atomic flush.
// ---------------------------------------------------------------------------
__global__ __launch_bounds__(512) void dsp_reduce(
    const float2* __restrict__ xab, const float2* __restrict__ xba,
    const int* __restrict__ src, const int* __restrict__ tar,
    float* __restrict__ sum_ab, float* __restrict__ sum_ba, int E)
{
    __shared__ float ls_ab[SC];
    __shared__ float ls_ba[SC];
    for (int i = threadIdx.x; i < SC; i += blockDim.x) {
        ls_ab[i] = 0.f;
        ls_ba[i] = 0.f;
    }
    __syncthreads();

    const int stride = gridDim.x * blockDim.x;
    for (int e = blockIdx.x * blockDim.x + threadIdx.x; e < E; e += stride) {
        float2 a = xab[e];
        float2 b = xba[e];
        int s = src[e];
        int t = tar[e];
        atomicAdd(&ls_ab[2 * s],     __expf(a.x));
        atomicAdd(&ls_ab[2 * s + 1], __expf(a.y));
        atomicAdd(&ls_ba[2 * t],     __expf(b.x));
        atomicAdd(&ls_ba[2 * t + 1], __expf(b.y));
    }
    __syncthreads();

    for (int i = threadIdx.x; i < SC; i += blockDim.x) {
        float va = ls_ab[i];
        float vb = ls_ba[i];
        if (va != 0.f) atomicAdd(&sum_ab[i], va);
        if (vb != 0.f) atomicAdd(&sum_ba[i], vb);
    }
}

// ---------------------------------------------------------------------------
// Pass 2: in-place reciprocal of the sum tables (16 K elements, trivial).
// ---------------------------------------------------------------------------
__global__ void dsp_rcp(float* __restrict__ sums, int n)
{
    int i = blockIdx.x * blockDim.x + threadIdx.x;
    if (i < n) {
        float v = sums[i];
        sums[i] = (v > 0.f) ? 1.f / v : 0.f;
    }
}

// ---------------------------------------------------------------------------
// Pass 3: normalize + write 3 outputs (prod, zab, zba) concatenated.
// ---------------------------------------------------------------------------
__global__ __launch_bounds__(256) void dsp_norm(
    const float2* __restrict__ xab, const float2* __restrict__ xba,
    const int* __restrict__ src, const int* __restrict__ tar,
    const float2* __restrict__ rcp_ab, const float2* __restrict__ rcp_ba,
    float2* __restrict__ out, int E)
{
    const int stride = gridDim.x * blockDim.x;
    for (int e = blockIdx.x * blockDim.x + threadIdx.x; e < E; e += stride) {
        float2 a = xab[e];
        float2 b = xba[e];
        int s = src[e];
        int t = tar[e];
        float2 ra = rcp_ab[s];
        float2 rb = rcp_ba[t];

        float2 zab = { __expf(a.x) * ra.x, __expf(a.y) * ra.y };
        float2 zba = { __expf(b.x) * rb.x, __expf(b.y) * rb.y };
        float2 prod = { zab.x * zba.x, zab.y * zba.y };

        out[e]         = prod;   // output 0: zab * zba
        out[E + e]     = zab;    // output 1: zab
        out[2 * E + e] = zba;    // output 2: zba
    }
}

extern "C" void kernel_launch(void* const* d_in, const int* in_sizes, int n_in,
                              void* d_out, int out_size, void* d_ws, size_t ws_size,
                              hipStream_t stream)
{
    const int E = in_sizes[0] / 2;
    const float2* xab = (const float2*)d_in[0];
    const float2* xba = (const float2*)d_in[1];
    const int*    src = (const int*)d_in[2];
    const int*    tar = (const int*)d_in[3];

    float* sum_ab = (float*)d_ws;
    float* sum_ba = sum_ab + SC;

    // ws is poisoned (0xAA) before timing and never re-poisoned: zero it
    // ourselves every call.
    hipMemsetAsync(d_ws, 0, 2 * SC * sizeof(float), stream);

    dsp_reduce<<<512, 512, 0, stream>>>(xab, xba, src, tar, sum_ab, sum_ba, E);
    dsp_rcp<<<(2 * SC + 255) / 256, 256, 0, stream>>>(sum_ab, 2 * SC);
    dsp_norm<<<2048, 256, 0, stream>>>(xab, xba, src, tar,
                                       (const float2*)sum_ab, (const float2*)sum_ba,
                                       (float2*)d_out, E);
}

// Round 3
// 408.635 us; speedup vs baseline: 1.4715x; 1.4715x over previous
//
#include <hip/hip_runtime.h>

#define NSEG 4096
#define QSCALE 131072.0f          // 2^17 fixed-point scale
#define QINV   (1.0f / 131072.0f)

typedef unsigned long long u64;
typedef unsigned int u32;
typedef float f32x4 __attribute__((ext_vector_type(4)));
typedef float f32x2 __attribute__((ext_vector_type(2)));

// ---------------------------------------------------------------------------
// Pass 1: per-segment sum of exp(x) for both (xab,src) and (xba,tar).
// Both channels packed into one u64 fixed-point LDS atomic (2 atomics/edge).
// Flush: per-block partial tables to global (no global atomics), or atomic
// fallback if ws is too small.
// ---------------------------------------------------------------------------
__global__ __launch_bounds__(1024, 8) void dsp_reduce(
    const f32x4* __restrict__ xab4, const f32x4* __restrict__ xba4,
    const int2* __restrict__ src2, const int2* __restrict__ tar2,
    float* __restrict__ partials,   // [gridDim.x][16384] floats, or nullptr
    float* __restrict__ gtab,       // fallback atomic table [16384], or nullptr
    int Eh)                          // E/2
{
    __shared__ u64 ls[2 * NSEG];    // [0,4096): ab table, [4096,8192): ba table
    for (int i = threadIdx.x; i < 2 * NSEG; i += 1024) ls[i] = 0ull;
    __syncthreads();

    const int stride = gridDim.x * 1024;
    for (int u = blockIdx.x * 1024 + threadIdx.x; u < Eh; u += stride) {
        f32x4 a = xab4[u];           // edges 2u, 2u+1 (ch0,ch1 each)
        f32x4 b = xba4[u];
        int2 s = src2[u];
        int2 t = tar2[u];

        u32 a0 = __float2uint_rn(__expf(a.x) * QSCALE);
        u32 a1 = __float2uint_rn(__expf(a.y) * QSCALE);
        u32 a2 = __float2uint_rn(__expf(a.z) * QSCALE);
        u32 a3 = __float2uint_rn(__expf(a.w) * QSCALE);
        atomicAdd(&ls[s.x], (u64)a0 | ((u64)a1 << 32));
        atomicAdd(&ls[s.y], (u64)a2 | ((u64)a3 << 32));

        u32 b0 = __float2uint_rn(__expf(b.x) * QSCALE);
        u32 b1 = __float2uint_rn(__expf(b.y) * QSCALE);
        u32 b2 = __float2uint_rn(__expf(b.z) * QSCALE);
        u32 b3 = __float2uint_rn(__expf(b.w) * QSCALE);
        atomicAdd(&ls[NSEG + t.x], (u64)b0 | ((u64)b1 << 32));
        atomicAdd(&ls[NSEG + t.y], (u64)b2 | ((u64)b3 << 32));
    }
    __syncthreads();

    if (partials) {
        float* dst = partials + (size_t)blockIdx.x * (4 * NSEG);
        for (int i = threadIdx.x; i < 2 * NSEG; i += 1024) {
            u64 v = ls[i];
            dst[2 * i]     = (float)(u32)v * QINV;          // channel 0
            dst[2 * i + 1] = (float)(u32)(v >> 32) * QINV;  // channel 1
        }
    } else {
        for (int i = threadIdx.x; i < 2 * NSEG; i += 1024) {
            u64 v = ls[i];
            float lo = (float)(u32)v * QINV;
            float hi = (float)(u32)(v >> 32) * QINV;
            if (lo != 0.f) atomicAdd(&gtab[2 * i], lo);
            if (hi != 0.f) atomicAdd(&gtab[2 * i + 1], hi);
        }
    }
}

// ---------------------------------------------------------------------------
// Pass 2a (partials path): column-sum 512 partial tables, store reciprocals.
// 4096 f32x4 columns == 16384 floats.
// ---------------------------------------------------------------------------
__global__ __launch_bounds__(256) void dsp_sum(
    const f32x4* __restrict__ partials, f32x4* __restrict__ rcp_out, int nb)
{
    int i = blockIdx.x * blockDim.x + threadIdx.x;   // 0..4095
    f32x4 acc = {0.f, 0.f, 0.f, 0.f};
    for (int p = 0; p < nb; ++p) {
        f32x4 v = __builtin_nontemporal_load(&partials[(size_t)p * NSEG + i]);
        acc += v;
    }
    f32x4 r;
    r.x = (acc.x > 0.f) ? 1.f / acc.x : 0.f;
    r.y = (acc.y > 0.f) ? 1.f / acc.y : 0.f;
    r.z = (acc.z > 0.f) ? 1.f / acc.z : 0.f;
    r.w = (acc.w > 0.f) ? 1.f / acc.w : 0.f;
    rcp_out[i] = r;
}

// ---------------------------------------------------------------------------
// Pass 2b (fallback path): in-place reciprocal of the sum tables.
// ---------------------------------------------------------------------------
__global__ void dsp_rcp(float* __restrict__ sums, int n)
{
    int i = blockIdx.x * blockDim.x + threadIdx.x;
    if (i < n) {
        float v = sums[i];
        sums[i] = (v > 0.f) ? 1.f / v : 0.f;
    }
}

// ---------------------------------------------------------------------------
// Pass 3: normalize + write 3 outputs (prod, zab, zba), 2 edges per thread.
// ---------------------------------------------------------------------------
__global__ __launch_bounds__(256) void dsp_norm(
    const f32x4* __restrict__ xab4, const f32x4* __restrict__ xba4,
    const int2* __restrict__ src2, const int2* __restrict__ tar2,
    const f32x2* __restrict__ rcp_ab, const f32x2* __restrict__ rcp_ba,
    f32x4* __restrict__ out, int Eh)
{
    const int stride = gridDim.x * blockDim.x;
    for (int u = blockIdx.x * blockDim.x + threadIdx.x; u < Eh; u += stride) {
        f32x4 a = __builtin_nontemporal_load(&xab4[u]);
        f32x4 b = __builtin_nontemporal_load(&xba4[u]);
        int2 s = src2[u];
        int2 t = tar2[u];
        f32x2 ra0 = rcp_ab[s.x], ra1 = rcp_ab[s.y];
        f32x2 rb0 = rcp_ba[t.x], rb1 = rcp_ba[t.y];

        f32x4 zab = { __expf(a.x) * ra0.x, __expf(a.y) * ra0.y,
                      __expf(a.z) * ra1.x, __expf(a.w) * ra1.y };
        f32x4 zba = { __expf(b.x) * rb0.x, __expf(b.y) * rb0.y,
                      __expf(b.z) * rb1.x, __expf(b.w) * rb1.y };
        f32x4 prod = zab * zba;

        __builtin_nontemporal_store(prod, &out[u]);            // zab*zba
        __builtin_nontemporal_store(zab,  &out[Eh + u]);       // zab
        __builtin_nontemporal_store(zba,  &out[2 * Eh + u]);   // zba
    }
}

extern "C" void kernel_launch(void* const* d_in, const int* in_sizes, int n_in,
                              void* d_out, int out_size, void* d_ws, size_t ws_size,
                              hipStream_t stream)
{
    const int E  = in_sizes[0] / 2;
    const int Eh = E / 2;
    const f32x4* xab4 = (const f32x4*)d_in[0];
    const f32x4* xba4 = (const f32x4*)d_in[1];
    const int2*  src2 = (const int2*)d_in[2];
    const int2*  tar2 = (const int2*)d_in[3];

    const int NB = 512;                       // reduce blocks (= partial count)
    float* rcp_tab  = (float*)d_ws;           // 16384 floats: ab at [0,8192), ba at [8192,16384)
    float* partials = (float*)((char*)d_ws + 65536);
    size_t need = 65536 + (size_t)NB * 65536; // 64 KB tables + 32 MB partials

    if (ws_size >= need) {
        dsp_reduce<<<NB, 1024, 0, stream>>>(xab4, xba4, src2, tar2,
                                            partials, nullptr, Eh);
        dsp_sum<<<NSEG / 256, 256, 0, stream>>>((const f32x4*)partials,
                                                (f32x4*)rcp_tab, NB);
    } else {
        (void)hipMemsetAsync(d_ws, 0, 65536, stream);
        dsp_reduce<<<NB, 1024, 0, stream>>>(xab4, xba4, src2, tar2,
                                            nullptr, rcp_tab, Eh);
        dsp_rcp<<<64, 256, 0, stream>>>(rcp_tab, 4 * NSEG);
    }

    dsp_norm<<<2048, 256, 0, stream>>>(xab4, xba4, src2, tar2,
                                       (const f32x2*)rcp_tab,
                                       (const f32x2*)(rcp_tab + 2 * NSEG),
                                       (f32x4*)d_out, Eh);
}

// Round 5
// 356.805 us; speedup vs baseline: 1.6852x; 1.1453x over previous
//
#include <hip/hip_runtime.h>

#define NSEG 4096
#define QSCALE 131072.0f          // 2^17 fixed-point scale
#define QINV   (1.0f / 131072.0f)

typedef unsigned long long u64;
typedef unsigned int u32;
typedef float f32x4 __attribute__((ext_vector_type(4)));
typedef float f32x2 __attribute__((ext_vector_type(2)));

// ---------------------------------------------------------------------------
// Pass 1: per-segment sum of exp(x), u64 fixed-point LDS atomics (2/edge),
// software-pipelined grid-stride loop (prefetch next iter before atomics).
// ---------------------------------------------------------------------------
__global__ __launch_bounds__(1024) void dsp_reduce(
    const f32x4* __restrict__ xab4, const f32x4* __restrict__ xba4,
    const int2* __restrict__ src2, const int2* __restrict__ tar2,
    float* __restrict__ partials,   // [gridDim.x][16384] floats, or nullptr
    float* __restrict__ gtab,       // fallback atomic table, or nullptr
    int Eh)
{
    __shared__ u64 ls[2 * NSEG];    // ab at [0,4096), ba at [4096,8192)
    for (int i = threadIdx.x; i < 2 * NSEG; i += 1024) ls[i] = 0ull;
    __syncthreads();

    const int stride = gridDim.x * 1024;
    int u = blockIdx.x * 1024 + threadIdx.x;

    f32x4 a, b; int2 s, t;
    if (u < Eh) { a = xab4[u]; b = xba4[u]; s = src2[u]; t = tar2[u]; }

    while (u < Eh) {
        // ---- prefetch next iteration (issues before the compute/atomics) ----
        int un = u + stride;
        f32x4 an, bn; int2 sn, tn;
        if (un < Eh) { an = xab4[un]; bn = xba4[un]; sn = src2[un]; tn = tar2[un]; }

        // ---- compute + LDS atomics on current ----
        u32 a0 = __float2uint_rn(__expf(a.x) * QSCALE);
        u32 a1 = __float2uint_rn(__expf(a.y) * QSCALE);
        u32 a2 = __float2uint_rn(__expf(a.z) * QSCALE);
        u32 a3 = __float2uint_rn(__expf(a.w) * QSCALE);
        atomicAdd(&ls[s.x], (u64)a0 | ((u64)a1 << 32));
        atomicAdd(&ls[s.y], (u64)a2 | ((u64)a3 << 32));

        u32 b0 = __float2uint_rn(__expf(b.x) * QSCALE);
        u32 b1 = __float2uint_rn(__expf(b.y) * QSCALE);
        u32 b2 = __float2uint_rn(__expf(b.z) * QSCALE);
        u32 b3 = __float2uint_rn(__expf(b.w) * QSCALE);
        atomicAdd(&ls[NSEG + t.x], (u64)b0 | ((u64)b1 << 32));
        atomicAdd(&ls[NSEG + t.y], (u64)b2 | ((u64)b3 << 32));

        u = un; a = an; b = bn; s = sn; t = tn;
    }
    __syncthreads();

    if (partials) {
        f32x2* dst = (f32x2*)(partials + (size_t)blockIdx.x * (4 * NSEG));
        for (int i = threadIdx.x; i < 2 * NSEG; i += 1024) {
            u64 v = ls[i];
            f32x2 w = { (float)(u32)v * QINV, (float)(u32)(v >> 32) * QINV };
            dst[i] = w;
        }
    } else {
        for (int i = threadIdx.x; i < 2 * NSEG; i += 1024) {
            u64 v = ls[i];
            float lo = (float)(u32)v * QINV;
            float hi = (float)(u32)(v >> 32) * QINV;
            if (lo != 0.f) atomicAdd(&gtab[2 * i], lo);
            if (hi != 0.f) atomicAdd(&gtab[2 * i + 1], hi);
        }
    }
}

// ---------------------------------------------------------------------------
// Pass 2a: column-sum NB partial tables, store reciprocals.
// ---------------------------------------------------------------------------
__global__ __launch_bounds__(256) void dsp_sum(
    const f32x4* __restrict__ partials, f32x4* __restrict__ rcp_out, int nb)
{
    int i = blockIdx.x * blockDim.x + threadIdx.x;   // 0..4095
    f32x4 acc = {0.f, 0.f, 0.f, 0.f};
    for (int p = 0; p < nb; ++p) {
        f32x4 v = __builtin_nontemporal_load(&partials[(size_t)p * NSEG + i]);
        acc += v;
    }
    f32x4 r;
    r.x = (acc.x > 0.f) ? 1.f / acc.x : 0.f;
    r.y = (acc.y > 0.f) ? 1.f / acc.y : 0.f;
    r.z = (acc.z > 0.f) ? 1.f / acc.z : 0.f;
    r.w = (acc.w > 0.f) ? 1.f / acc.w : 0.f;
    rcp_out[i] = r;
}

// ---------------------------------------------------------------------------
// Pass 2b (fallback): in-place reciprocal.
// ---------------------------------------------------------------------------
__global__ void dsp_rcp(float* __restrict__ sums, int n)
{
    int i = blockIdx.x * blockDim.x + threadIdx.x;
    if (i < n) {
        float v = sums[i];
        sums[i] = (v > 0.f) ? 1.f / v : 0.f;
    }
}

// ---------------------------------------------------------------------------
// Pass 3: normalize + write 3 outputs. rcp tables staged in LDS (64 KB),
// 1024-thread blocks (2 blocks/CU = 32 waves/CU), pipelined loop, NT stores.
// LDS float layout: ab rcp at [0, 2*NSEG), ba rcp at [2*NSEG, 4*NSEG).
// ---------------------------------------------------------------------------
__global__ __launch_bounds__(1024) void dsp_norm(
    const f32x4* __restrict__ xab4, const f32x4* __restrict__ xba4,
    const int2* __restrict__ src2, const int2* __restrict__ tar2,
    const f32x4* __restrict__ rcp_tab,   // 16384 floats: ab then ba
    f32x4* __restrict__ out, int Eh)
{
    __shared__ float ls[4 * NSEG];
    for (int i = threadIdx.x; i < NSEG; i += 1024)
        ((f32x4*)ls)[i] = rcp_tab[i];
    __syncthreads();

    const int stride = gridDim.x * 1024;
    int u = blockIdx.x * 1024 + threadIdx.x;

    f32x4 a, b; int2 s, t;
    if (u < Eh) { a = xab4[u]; b = xba4[u]; s = src2[u]; t = tar2[u]; }

    while (u < Eh) {
        // ---- prefetch next iteration ----
        int un = u + stride;
        f32x4 an, bn; int2 sn, tn;
        if (un < Eh) { an = xab4[un]; bn = xba4[un]; sn = src2[un]; tn = tar2[un]; }

        // ---- LDS gathers for current indices ----
        f32x2 ra0 = *(const f32x2*)&ls[2 * s.x];
        f32x2 ra1 = *(const f32x2*)&ls[2 * s.y];
        f32x2 rb0 = *(const f32x2*)&ls[2 * NSEG + 2 * t.x];   // ba table at +2*NSEG
        f32x2 rb1 = *(const f32x2*)&ls[2 * NSEG + 2 * t.y];

        f32x4 zab = { __expf(a.x) * ra0.x, __expf(a.y) * ra0.y,
                      __expf(a.z) * ra1.x, __expf(a.w) * ra1.y };
        f32x4 zba = { __expf(b.x) * rb0.x, __expf(b.y) * rb0.y,
                      __expf(b.z) * rb1.x, __expf(b.w) * rb1.y };
        f32x4 prod = zab * zba;

        __builtin_nontemporal_store(prod, &out[u]);            // zab*zba
        __builtin_nontemporal_store(zab,  &out[Eh + u]);       // zab
        __builtin_nontemporal_store(zba,  &out[2 * Eh + u]);   // zba

        u = un; a = an; b = bn; s = sn; t = tn;
    }
}

extern "C" void kernel_launch(void* const* d_in, const int* in_sizes, int n_in,
                              void* d_out, int out_size, void* d_ws, size_t ws_size,
                              hipStream_t stream)
{
    const int E  = in_sizes[0] / 2;
    const int Eh = E / 2;
    const f32x4* xab4 = (const f32x4*)d_in[0];
    const f32x4* xba4 = (const f32x4*)d_in[1];
    const int2*  src2 = (const int2*)d_in[2];
    const int2*  tar2 = (const int2*)d_in[3];

    const int NB = 512;                       // reduce blocks (= partial count)
    float* rcp_tab  = (float*)d_ws;           // 16384 floats
    float* partials = (float*)((char*)d_ws + 65536);
    size_t need = 65536 + (size_t)NB * 65536;

    if (ws_size >= need) {
        dsp_reduce<<<NB, 1024, 0, stream>>>(xab4, xba4, src2, tar2,
                                            partials, nullptr, Eh);
        dsp_sum<<<NSEG / 256, 256, 0, stream>>>((const f32x4*)partials,
                                                (f32x4*)rcp_tab, NB);
    } else {
        (void)hipMemsetAsync(d_ws, 0, 65536, stream);
        dsp_reduce<<<NB, 1024, 0, stream>>>(xab4, xba4, src2, tar2,
                                            nullptr, rcp_tab, Eh);
        dsp_rcp<<<64, 256, 0, stream>>>(rcp_tab, 4 * NSEG);
    }

    dsp_norm<<<512, 1024, 0, stream>>>(xab4, xba4, src2, tar2,
                                       (const f32x4*)rcp_tab,
                                       (f32x4*)d_out, Eh);
}